// Round 6
// baseline (17.941 us; speedup 1.0000x reference)
//
#include <hip/hip_runtime.h>
#include <math.h>

// ---- hand-inlined f64 exp/log (no libm calls -> no ABI spills/scratch) ----
// dexp: e^t for |t| <= 45, rel err ~7e-12
__device__ __forceinline__ double dexp(double t) {
    const double LOG2E  = 1.4426950408889634;
    const double LN2_HI = 6.93147180369123816490e-01;
    const double LN2_LO = 1.90821492927058770002e-10;
    double kd = __builtin_floor(t * LOG2E + 0.5);
    double f  = (t - kd * LN2_HI) - kd * LN2_LO;   // |f| <= 0.3466
    double p = 1.0 / 362880.0;
    p = p * f + 1.0 / 40320.0;
    p = p * f + 1.0 / 5040.0;
    p = p * f + 1.0 / 720.0;
    p = p * f + 1.0 / 120.0;
    p = p * f + 1.0 / 24.0;
    p = p * f + 1.0 / 6.0;
    p = p * f + 0.5;
    p = p * f + 1.0;
    p = p * f + 1.0;
    long long k = (long long)kd;                    // |k| <= 66: exponent-add safe
    return __longlong_as_double(__double_as_longlong(p) + (k << 52));
}
// dlog: ln(y) for y in [1e-10, 16], rel err ~1e-12; exact-grade near y=1
// (m-1 exact by Sterbenz, e=0 -> no ln2 rounding), which is the case that matters.
__device__ __forceinline__ double dlog(double y) {
    long long b = __double_as_longlong(y);
    int e = (int)((b >> 52) & 0x7FF) - 1022;        // m in [0.5,1)
    double m = __longlong_as_double((b & 0x000FFFFFFFFFFFFFLL) | 0x3FE0000000000000LL);
    if (m < 0.7071067811865476) { m = m + m; e -= 1; }   // m in [sqrt(1/2), sqrt(2))
    double s  = (m - 1.0) / (m + 1.0);              // |s| <= 0.1716
    double s2 = s * s;
    double p = 1.0 / 15.0;
    p = p * s2 + 1.0 / 13.0;
    p = p * s2 + 1.0 / 11.0;
    p = p * s2 + 1.0 / 9.0;
    p = p * s2 + 1.0 / 7.0;
    p = p * s2 + 1.0 / 5.0;
    p = p * s2 + 1.0 / 3.0;
    p = p * s2 + 1.0;
    return (double)e * 0.6931471805599453 + 2.0 * s * p;
}

__device__ __forceinline__ float fast_sin(float th) {
    float rev = th * 0.15915494309189535f;
    rev = rev - floorf(rev);                        // folds to v_fract_f32
    return __builtin_amdgcn_sinf(rev);
}

struct W {
    float w0, w1, w2, w3;
    float c5, c6, c7, c8;          // folded: n11/n14/n18 into n5,n6; n12 into n7,n8
    float w9, w10, w13, w15, w16, c17;
    float base;                    // bias + 2.5*w4
};

__device__ __forceinline__ float eval_row(const W& q, float x0, float x1, float x2, float x3) {
    float n5 = 1.1f * fast_sin(fmaf(1.3f, x0, 0.2f));
    float t6 = fabsf(x1) + 1e-10f;
    float n6 = t6 * t6;
    float y2 = fabsf(x2) + 1e-10f;
    float sgn2 = (x2 > 0.f) ? 1.f : ((x2 < 0.f) ? -1.f : 0.f);
    float n7 = sgn2 * __expf(1.7f * __logf(y2));
    float n8 = __expf(fminf(fmaxf(0.5f * x3, -20.f), 20.f));
    float n9 = __logf(fabsf(x0) + 1e-10f);
    float n10 = x1 * x1 * x1;
    float n11 = n5 + n6;
    float n12 = n7 - n8;
    float n13 = n9 * n10;
    float n14 = 0.4f * n11;

    // n15 = safe_div(n12, n13): fast f32 (only node whose clip can trigger)
    float a13 = fabsf(n13);
    float sgn13 = (n13 > 0.f) ? 1.f : ((n13 < 0.f) ? -1.f : 0.f);
    float n15 = n12 * __builtin_amdgcn_rcpf(a13 + 1e-10f) * sgn13;
    n15 = fminf(fmaxf(n15, -1.0e6f), 1.0e6f);

    // Tier-2: |n13|<1e-7 & |n12|>=0.25 -> result is exactly the +/-1e6 clip.
    // sign(n13) computed exactly: sign(log(|x0|+1e-10)) <=> |x0| >= 1.0f on f32 grid.
    bool flag = a13 < 1e-7f;
    if (flag) {
        float s13 = (x1 == 0.f) ? 0.f
                  : (((fabsf(x0) >= 1.0f) == (x1 > 0.f)) ? 1.f : -1.f);
        n15 = copysignf(1.0e6f, n12) * s13;
    }
    // Tier-3 (rare): flagged with small numerator, or |x0| near +/-1 (f32 log
    // abs-error zone). Full f64 recompute via inline series -- no libm calls.
    bool x0n1 = fabsf(fabsf(x0) - 1.0f) < 1e-4f;
    if ((flag && fabsf(n12) < 0.25f) || x0n1) {
        double n7d = (double)sgn2 * dexp(1.7 * dlog(fabs((double)x2) + 1e-10));
        double n8d = dexp(fmin(fmax(0.5 * (double)x3, -20.0), 20.0));
        double n9d = dlog(fabs((double)x0) + 1e-10);
        double x1d = (double)x1;
        double n12d = n7d - n8d;                       // |.| <= 52, no clip active
        double n13d = n9d * (x1d * x1d * x1d);         // |.| <= ~8e3, no clip active
        double sd = (n13d > 0.0) ? 1.0 : ((n13d < 0.0) ? -1.0 : 0.0);
        double rr = n12d / (fabs(n13d) + 1e-10) * sd;
        n15 = (float)fmin(fmax(rr, -1.0e6), 1.0e6);
    }

    // n16 = tau=0.5 softmax-combine(n14,n15) = n15 + d*sigmoid(2d)
    float d = n14 - n15;
    float s = __builtin_amdgcn_rcpf(1.0f + __expf(-2.0f * d));  // exact 0/1 at saturation
    float n16 = n15 + d * s;
    float n17 = 0.9f * fast_sin(fmaf(0.7f, n16, -0.3f));

    float r = q.base;
    r += q.w0 * x0 + q.w1 * x1 + q.w2 * x2 + q.w3 * x3;
    r += q.c5 * n5 + q.c6 * n6 + q.c7 * n7 + q.c8 * n8;
    r += q.w9 * n9 + q.w10 * n10 + q.w13 * n13;
    r += q.w15 * n15 + q.w16 * n16 + q.c17 * n17;
    return r;
}

__global__ void __launch_bounds__(256) graph_eval(
    const float4* __restrict__ x4,     // rows of 8 floats; first float4 of each used
    const float*  __restrict__ w,
    const float*  __restrict__ bias,
    float2*       __restrict__ out2,
    int nhalf)                          // n/2 (n even)
{
    int j = blockIdx.x * blockDim.x + threadIdx.x;
    if (j >= nhalf) return;

    float4 a = x4[4 * j];
    float4 b = x4[4 * j + 2];

    W q;
    float c11 = w[11] + 0.4f * w[14] + w[18];
    q.w0 = w[0];  q.w1 = w[1];  q.w2 = w[2];  q.w3 = w[3];
    q.c5 = w[5] + c11;  q.c6 = w[6] + c11;
    q.c7 = w[7] + w[12];  q.c8 = w[8] - w[12];
    q.w9 = w[9];  q.w10 = w[10];  q.w13 = w[13];
    q.w15 = w[15];  q.w16 = w[16];  q.c17 = w[17] + w[18];
    q.base = bias[0] + 2.5f * w[4];

    float r0 = eval_row(q, a.x, a.y, a.z, a.w);
    float r1 = eval_row(q, b.x, b.y, b.z, b.w);
    out2[j] = make_float2(r0, r1);
}

extern "C" void kernel_launch(void* const* d_in, const int* in_sizes, int n_in,
                              void* d_out, int out_size, void* d_ws, size_t ws_size,
                              hipStream_t stream) {
    const float4* x  = (const float4*)d_in[0];
    const float*  w  = (const float*)d_in[1];
    const float*  b  = (const float*)d_in[2];
    float2* out = (float2*)d_out;
    int nhalf = out_size / 2;
    int block = 256;
    int grid = (nhalf + block - 1) / block;
    graph_eval<<<grid, block, 0, stream>>>(x, w, b, out, nhalf);
}